// Round 18
// baseline (154.035 us; speedup 1.0000x reference)
//
#include <hip/hip_runtime.h>
#include <math.h>

#define N_PIX 65536
#define EPSF 1e-6f
#define CHUNKS 32
#define PX_PER_CHUNK 2048   // 65536 / 32
#define PX_PER_WAVE 512     // 4 waves per block, 8 super-tiles of 64 px
#define N_TILES (PX_PER_WAVE / 64)
#define N_JOBS 48           // 2 imgs * 8 batch * 3 channels
#define N_BLOCKS (N_JOBS * CHUNKS)   // 1536
#define N_RBLOCKS (24 * 4)           // 96 reduce blocks (f32x4 per thread)
#define LN2_50 34.65735903f // 50 * ln(2): log2 -> scaled-ln

typedef __attribute__((ext_vector_type(2))) float f2;
using short8 = __attribute__((ext_vector_type(8))) short;
using f32x4  = __attribute__((ext_vector_type(4))) float;

__device__ __forceinline__ float rcp_fast(float x) { return __builtin_amdgcn_rcpf(x); }

#if __has_builtin(__builtin_amdgcn_cvt_pk_bf16_f32)
typedef __attribute__((ext_vector_type(2))) __bf16 bf16x2_t;
__device__ __forceinline__ uint32_t pk_bf16(float a, float b) {
    return __builtin_bit_cast(uint32_t, __builtin_amdgcn_cvt_pk_bf16_f32(a, b));
}
#else
// fallback: round-half-up (inputs positive finite), 3 ops
__device__ __forceinline__ uint32_t pk_bf16(float a, float b) {
    const uint32_t ua = __builtin_bit_cast(uint32_t, a) + 0x8000u;
    const uint32_t ub = __builtin_bit_cast(uint32_t, b) + 0x8000u;
    return __builtin_amdgcn_perm(ub, ua, 0x07060302u);
}
#endif

// phase A: pixel -> (u*50, v*50, weight); log2-based (ln2 folded into scale)
__device__ __forceinline__ float4 phaseA(float pr, float pg, float pb, int c) {
    const float r  = pr + EPSF;
    const float g  = pg + EPSF;
    const float bl = pb + EPSF;
    const float wgt = sqrtf(fmaf(r, r, fmaf(g, g, bl * bl)));
    const float lr = __log2f(r), lg = __log2f(g), lb2 = __log2f(bl);
    // channel c: u = l_c - l_a, v = l_c - l_b;  c0:(a,b)=(g,b) c1:(r,b) c2:(r,g)
    const float l0 = (c == 0) ? lr : ((c == 1) ? lg : lb2);
    const float lu = (c == 0) ? lg : lr;
    const float lv = (c == 2) ? lg : lb2;
    return make_float4((l0 - lu) * LN2_50, (l0 - lv) * LN2_50, wgt, 0.0f);
}

// ---------------------------------------------------------------------------
// Kernel 1: per (job, chunk) partial 64x64 histogram via bf16 MFMA with
// fragment-direct operand generation. R18: balanced-pipe eval.
// Pipe model (fits R16 AND R17 at ~82us eval): per-eval main-pipe/trans
// cycles — R16 rcp-of-4 scalar-unwind = 8/2 (main-bound), R17 rcp-per-denom
// = 3.5/8 (trans-bound, quarter-rate trans). R18 uses rcp-of-2-product with
// the unwind as a PACKED pk_mul (swizzled {q.y,q.x} operand -> v_pk_mul_f32
// op_sel): per 2 evals = 1 product mul + 1 rcp + 1 pk_mul (+ shared
// pk_add/pk_fma/pack) -> 5.5/4 cyc per eval, both pipes under either old
// bound. rcp-of-product err ~2-3 ulp fp32, invisible under bf16.
// Everything else R16/R17: 1536 blocks (6/CU; regfile-capped 4 waves/SIMD),
// contiguous b128 partial stores, conflict-free padded staging.
// Block 0 zeroes accum[24]+ticket.
// ---------------------------------------------------------------------------
__global__ __launch_bounds__(256, 4) void hist_kernel(
    const float* __restrict__ x, const float* __restrict__ y,
    float* __restrict__ partial, float* __restrict__ accum)
{
    const int blk = blockIdx.x;            // 0..1535
    const int chunk = blk & (CHUNKS - 1);
    const int job = blk / CHUNKS;          // 0..47
    const int c = job % 3;
    const int ib = job / 3;                // img*8 + b
    const int img = ib >> 3;
    const int b = ib & 7;
    const float* __restrict__ src = (img == 0 ? x : y) + (size_t)b * 3 * N_PIX;

    const int tid = threadIdx.x;
    if (blk == 0 && tid < 25) ((unsigned*)accum)[tid] = 0u;  // accum[24] + ticket

    __shared__ __align__(16) float lds[4096];   // 16 KB: wbufs / epilogue strips
    const int lane = tid & 63;
    const int wv = tid >> 6;
    float* __restrict__ wbuf = lds + wv * 288;  // 64 px * float4, +16B pad per 8 px

    const int quad = lane >> 4;
    const int l15 = lane & 15;
    // negated scaled centers for this lane's 4 m-rows: -(c_m * 50), m = mt*16+l15
    f2 ncb01, ncb23;
    {
        const float c0 = (-3.0f + (float)(l15)      * (6.0f / 63.0f)) * 50.0f;
        const float c1 = (-3.0f + (float)(16 + l15) * (6.0f / 63.0f)) * 50.0f;
        const float c2 = (-3.0f + (float)(32 + l15) * (6.0f / 63.0f)) * 50.0f;
        const float c3 = (-3.0f + (float)(48 + l15) * (6.0f / 63.0f)) * 50.0f;
        ncb01 = (f2){-c0, -c1};
        ncb23 = (f2){-c2, -c3};
    }
    const f2 one2 = {1.0f, 1.0f};

    f32x4 acc[16];                         // acc[mt*4+nt]
#pragma unroll
    for (int i = 0; i < 16; ++i) acc[i] = (f32x4){0.f, 0.f, 0.f, 0.f};

    const int px0 = chunk * PX_PER_CHUNK + wv * PX_PER_WAVE;

    // prefetch super-tile 0
    float pr, pg, pb;
    {
        const int n = px0 + lane;
        pr = src[n]; pg = src[N_PIX + n]; pb = src[2 * N_PIX + n];
    }

#pragma unroll 1
    for (int st = 0; st < N_TILES; ++st) {
        // ---- Phase A: one pixel per lane; stage to LDS (same-wave, in-order) ----
        const float4 uvw = phaseA(pr, pg, pb, c);
        *(float4*)(wbuf + lane * 4 + (lane >> 3) * 4) = uvw;

        if (st + 1 < N_TILES) {            // prefetch next tile's raw pixels
            const int n2 = px0 + (st + 1) * 64 + lane;
            pr = src[n2]; pg = src[N_PIX + n2]; pb = src[2 * N_PIX + n2];
        }

#pragma unroll
        for (int h = 0; h < 2; ++h) {              // two K=32 halves
            const int base = h * 32 + quad * 8;    // first pixel this lane consumes
            const float4* __restrict__ pbase =
                (const float4*)(wbuf + base * 4 + (base >> 3) * 4);
            int aU[4][4], aV[4][4];                // fragment words [mt][jp]

#pragma unroll
            for (int jp = 0; jp < 4; ++jp) {       // j = 2jp (even), 2jp+1 (odd)
                const float4 pe = pbase[2 * jp];
                const float4 po = pbase[2 * jp + 1];

                f2 aue01, aue23, auo01, auo23;
                f2 bve01, bve23, bvo01, bvo23;
#pragma unroll
                for (int eo = 0; eo < 2; ++eo) {
                    const float ru = eo ? po.x : pe.x;
                    const float rv = eo ? po.y : pe.y;
                    const float rw = eo ? po.z : pe.z;
                    const f2 ru2 = {ru, ru}, rv2 = {rv, rv};
                    const f2 tu01 = ru2 + ncb01, tu23 = ru2 + ncb23;
                    const f2 tv01 = rv2 + ncb01, tv23 = rv2 + ncb23;
                    const f2 qu01 = __builtin_elementwise_fma(tu01, tu01, one2);
                    const f2 qu23 = __builtin_elementwise_fma(tu23, tu23, one2);
                    const f2 qv01 = __builtin_elementwise_fma(tv01, tv01, one2);
                    const f2 qv23 = __builtin_elementwise_fma(tv23, tv23, one2);
                    // rcp-of-2-product + packed swizzled unwind (1 pk_mul per pair);
                    // w folded into the U reciprocals (scalar, before unwind).
                    const float RU01 = rcp_fast(qu01.x * qu01.y) * rw;
                    const float RU23 = rcp_fast(qu23.x * qu23.y) * rw;
                    const float RV01 = rcp_fast(qv01.x * qv01.y);
                    const float RV23 = rcp_fast(qv23.x * qv23.y);
                    const f2 au01 = (f2){RU01, RU01} * (f2){qu01.y, qu01.x};
                    const f2 au23 = (f2){RU23, RU23} * (f2){qu23.y, qu23.x};
                    const f2 bv01 = (f2){RV01, RV01} * (f2){qv01.y, qv01.x};
                    const f2 bv23 = (f2){RV23, RV23} * (f2){qv23.y, qv23.x};
                    if (eo) { auo01 = au01; auo23 = au23; bvo01 = bv01; bvo23 = bv23; }
                    else    { aue01 = au01; aue23 = au23; bve01 = bv01; bve23 = bv23; }
                }
                aU[0][jp] = pk_bf16(aue01.x, auo01.x);   // mt0 <- center c0
                aU[1][jp] = pk_bf16(aue01.y, auo01.y);   // mt1 <- c1
                aU[2][jp] = pk_bf16(aue23.x, auo23.x);   // mt2 <- c2
                aU[3][jp] = pk_bf16(aue23.y, auo23.y);   // mt3 <- c3
                aV[0][jp] = pk_bf16(bve01.x, bvo01.x);
                aV[1][jp] = pk_bf16(bve01.y, bvo01.y);
                aV[2][jp] = pk_bf16(bve23.x, bvo23.x);
                aV[3][jp] = pk_bf16(bve23.y, bvo23.y);
            }

            short8 af[4], bf[4];
#pragma unroll
            for (int mt = 0; mt < 4; ++mt) {
                af[mt] = __builtin_bit_cast(short8,
                    make_int4(aU[mt][0], aU[mt][1], aU[mt][2], aU[mt][3]));
                bf[mt] = __builtin_bit_cast(short8,
                    make_int4(aV[mt][0], aV[mt][1], aV[mt][2], aV[mt][3]));
            }
#pragma unroll
            for (int mt = 0; mt < 4; ++mt)
#pragma unroll
                for (int nt = 0; nt < 4; ++nt)
                    acc[mt * 4 + nt] = __builtin_amdgcn_mfma_f32_16x16x32_bf16(
                        af[mt], bf[nt], acc[mt * 4 + nt], 0, 0, 0);
        }
    }

    // ---- Atomic-free epilogue: 4 chunks over mt; ALL traffic linear b128 ----
    float* __restrict__ outp = partial + (size_t)blk * 4096;
#pragma unroll 1
    for (int ch = 0; ch < 4; ++ch) {
        __syncthreads();                   // previous chunk (or main loop) done
#pragma unroll
        for (int nt = 0; nt < 4; ++nt)     // wave strip: [wv][nt*256 + lane*4 + i]
            *(f32x4*)(lds + wv * 1024 + nt * 256 + lane * 4) = acc[ch * 4 + nt];
        __syncthreads();
        const int e4 = tid * 4;            // 0..1023, linear -> conflict-free b128
        const f32x4 s0 = *(const f32x4*)(lds +        e4);
        const f32x4 s1 = *(const f32x4*)(lds + 1024 + e4);
        const f32x4 s2 = *(const f32x4*)(lds + 2048 + e4);
        const f32x4 s3 = *(const f32x4*)(lds + 3072 + e4);
        const f32x4 s = (s0 + s1) + (s2 + s3);
        // contiguous f32x4 store in wave-strip element order (no permutation;
        // bin mapping is job-independent so element e is consistent x vs y)
        *(f32x4*)(outp + ch * 1024 + e4) = s;
    }
}

// ---------------------------------------------------------------------------
// Kernel 2: Bhattacharyya-factored reduction + fused finalize.
//   sum (sqrt(y/TY)-sqrt(x/TX))^2 = 2(1 - rho), rho = sum sqrt(sx*sy)/sqrt(TX*TY)
// 96 blocks x 256 (24 x-jobs x 4 slices): each thread owns one element-QUAD;
// accumulates qx, qy over the 32 chunk-partials with contiguous f32x4 loads,
// then sx=Σqx, sy=Σqy, cr=Σ sqrt(qx*qy). Block-reduce 3 scalars, 3 device
// atomicAdds; tid0 RELEASE-ticket; the 96th block ACQUIRE-loads accum and
// writes out[0].
// ---------------------------------------------------------------------------
__global__ __launch_bounds__(256) void reduce_cross_kernel(
    const float* __restrict__ partial, float* __restrict__ accum,
    float* __restrict__ out)
{
    unsigned* __restrict__ ticket = (unsigned*)(accum + 24);
    const int jx = blockIdx.x >> 2;                        // 0..23 (img0 job)
    const int bb = jx / 3;                                 // batch 0..7
    const int e4 = (((blockIdx.x & 3) << 8) | threadIdx.x) * 4;  // 0..4092
    const float* px = partial + (size_t)jx * CHUNKS * 4096 + e4;
    const float* py = partial + (size_t)(24 + jx) * CHUNKS * 4096 + e4;

    f32x4 qx = {0.f, 0.f, 0.f, 0.f}, qy = {0.f, 0.f, 0.f, 0.f};
#pragma unroll 8
    for (int k = 0; k < CHUNKS; ++k) {
        qx += *(const f32x4*)(px + (size_t)k * 4096);
        qy += *(const f32x4*)(py + (size_t)k * 4096);
    }
    float sx = (qx.x + qx.y) + (qx.z + qx.w);
    float sy = (qy.x + qy.y) + (qy.z + qy.w);
    float cr = (sqrtf(qx.x * qy.x) + sqrtf(qx.y * qy.y)) +
               (sqrtf(qx.z * qy.z) + sqrtf(qx.w * qy.w));

#pragma unroll
    for (int o = 32; o > 0; o >>= 1) {
        sx += __shfl_down(sx, o, 64);
        sy += __shfl_down(sy, o, 64);
        cr += __shfl_down(cr, o, 64);
    }
    __shared__ float red[12];
    const int wv = threadIdx.x >> 6;
    if ((threadIdx.x & 63) == 0) {
        red[wv] = sx; red[4 + wv] = sy; red[8 + wv] = cr;
    }
    __syncthreads();
    if (threadIdx.x == 0) {
        atomicAdd(&accum[bb],      red[0] + red[1] + red[2] + red[3]);
        atomicAdd(&accum[8 + bb],  red[4] + red[5] + red[6] + red[7]);
        atomicAdd(&accum[16 + bb], red[8] + red[9] + red[10] + red[11]);
        const unsigned old = __hip_atomic_fetch_add(ticket, 1u,
                                 __ATOMIC_ACQ_REL, __HIP_MEMORY_SCOPE_AGENT);
        if (old == N_RBLOCKS - 1) {        // last arriver: all atomicAdds visible
            float s = 0.0f;
#pragma unroll
            for (int b = 0; b < 8; ++b) {
                const float tx = __hip_atomic_load(&accum[b],      __ATOMIC_ACQUIRE, __HIP_MEMORY_SCOPE_AGENT);
                const float ty = __hip_atomic_load(&accum[8 + b],  __ATOMIC_ACQUIRE, __HIP_MEMORY_SCOPE_AGENT);
                const float cc = __hip_atomic_load(&accum[16 + b], __ATOMIC_ACQUIRE, __HIP_MEMORY_SCOPE_AGENT);
                const float rho = cc * __builtin_amdgcn_rsqf(tx * ty);
                s += sqrtf(fmaxf(1.0f - rho, 0.0f));
            }
            out[0] = s * 0.125f;
        }
    }
}

extern "C" void kernel_launch(void* const* d_in, const int* in_sizes, int n_in,
                              void* d_out, int out_size, void* d_ws, size_t ws_size,
                              hipStream_t stream)
{
    const float* x = (const float*)d_in[0];
    const float* y = (const float*)d_in[1];
    float* ws = (float*)d_ws;
    float* partial = ws;                                  // 1536*4096 floats (25.2 MB)
    float* accum = ws + (size_t)N_BLOCKS * 4096;          // 24 floats + ticket
    float* outf = (float*)d_out;

    hipLaunchKernelGGL(hist_kernel, dim3(N_BLOCKS), dim3(256), 0, stream,
                       x, y, partial, accum);
    hipLaunchKernelGGL(reduce_cross_kernel, dim3(N_RBLOCKS), dim3(256), 0, stream,
                       partial, accum, outf);
}

// Round 19
// 148.414 us; speedup vs baseline: 1.0379x; 1.0379x over previous
//
#include <hip/hip_runtime.h>
#include <math.h>

#define N_PIX 65536
#define EPSF 1e-6f
#define CHUNKS 32
#define PX_PER_CHUNK 2048   // 65536 / 32
#define PX_PER_WAVE 512     // 4 waves per block, 8 super-tiles of 64 px
#define N_TILES (PX_PER_WAVE / 64)
#define N_JOBS 48           // 2 imgs * 8 batch * 3 channels
#define N_BLOCKS (N_JOBS * CHUNKS)   // 1536
#define N_RBLOCKS (24 * 4)           // 96 reduce blocks (f32x4 per thread)
#define LN2_50 34.65735903f // 50 * ln(2): log2 -> scaled-ln

typedef __attribute__((ext_vector_type(2))) float f2;
using short8 = __attribute__((ext_vector_type(8))) short;
using f32x4  = __attribute__((ext_vector_type(4))) float;

__device__ __forceinline__ float rcp_fast(float x) { return __builtin_amdgcn_rcpf(x); }

#if __has_builtin(__builtin_amdgcn_cvt_pk_bf16_f32)
typedef __attribute__((ext_vector_type(2))) __bf16 bf16x2_t;
__device__ __forceinline__ uint32_t pk_bf16(float a, float b) {
    return __builtin_bit_cast(uint32_t, __builtin_amdgcn_cvt_pk_bf16_f32(a, b));
}
#else
// fallback: round-half-up (inputs positive finite), 3 ops
__device__ __forceinline__ uint32_t pk_bf16(float a, float b) {
    const uint32_t ua = __builtin_bit_cast(uint32_t, a) + 0x8000u;
    const uint32_t ub = __builtin_bit_cast(uint32_t, b) + 0x8000u;
    return __builtin_amdgcn_perm(ub, ua, 0x07060302u);
}
#endif

// phase A: pixel -> (u*50, v*50, weight); log2-based (ln2 folded into scale)
__device__ __forceinline__ float4 phaseA(float pr, float pg, float pb, int c) {
    const float r  = pr + EPSF;
    const float g  = pg + EPSF;
    const float bl = pb + EPSF;
    const float wgt = sqrtf(fmaf(r, r, fmaf(g, g, bl * bl)));
    const float lr = __log2f(r), lg = __log2f(g), lb2 = __log2f(bl);
    // channel c: u = l_c - l_a, v = l_c - l_b;  c0:(a,b)=(g,b) c1:(r,b) c2:(r,g)
    const float l0 = (c == 0) ? lr : ((c == 1) ? lg : lb2);
    const float lu = (c == 0) ? lg : lr;
    const float lv = (c == 2) ? lg : lb2;
    return make_float4((l0 - lu) * LN2_50, (l0 - lv) * LN2_50, wgt, 0.0f);
}

// ---------------------------------------------------------------------------
// Kernel 1: per (job, chunk) partial 64x64 histogram via bf16 MFMA with
// fragment-direct operand generation. R19 = R17 verbatim (best: 148.8us
// total, k1 89us). R18 post-mortem CLOSED the eval-mix question: R16
// main-heavy (96us), R17 trans-heavy (89us), R18 balanced (93us) — 40%
// issue-count spread, same ~90us duration. The binding constraint is the
// structural dependency spine (phase-A trans chain -> LDS round-trip ->
// broadcast read -> MFMA) at the regfile-capped 4 waves/SIMD, not the
// VALU/trans instruction mix. This structure is at its practical plateau.
// Phase-B eval (R17): one v_rcp per denominator, fully-packed f2 ops; the
// quarter-rate trans pipe co-issues with VALU; V's rcp IS the value.
// 1536 blocks (6/CU), contiguous b128 partial stores (wave-strip element
// order, permutation-free), conflict-free padded staging (R5-verified).
// Block 0 zeroes accum[24]+ticket.
// ---------------------------------------------------------------------------
__global__ __launch_bounds__(256, 4) void hist_kernel(
    const float* __restrict__ x, const float* __restrict__ y,
    float* __restrict__ partial, float* __restrict__ accum)
{
    const int blk = blockIdx.x;            // 0..1535
    const int chunk = blk & (CHUNKS - 1);
    const int job = blk / CHUNKS;          // 0..47
    const int c = job % 3;
    const int ib = job / 3;                // img*8 + b
    const int img = ib >> 3;
    const int b = ib & 7;
    const float* __restrict__ src = (img == 0 ? x : y) + (size_t)b * 3 * N_PIX;

    const int tid = threadIdx.x;
    if (blk == 0 && tid < 25) ((unsigned*)accum)[tid] = 0u;  // accum[24] + ticket

    __shared__ __align__(16) float lds[4096];   // 16 KB: wbufs / epilogue strips
    const int lane = tid & 63;
    const int wv = tid >> 6;
    float* __restrict__ wbuf = lds + wv * 288;  // 64 px * float4, +16B pad per 8 px

    const int quad = lane >> 4;
    const int l15 = lane & 15;
    // negated scaled centers for this lane's 4 m-rows: -(c_m * 50), m = mt*16+l15
    f2 ncb01, ncb23;
    {
        const float c0 = (-3.0f + (float)(l15)      * (6.0f / 63.0f)) * 50.0f;
        const float c1 = (-3.0f + (float)(16 + l15) * (6.0f / 63.0f)) * 50.0f;
        const float c2 = (-3.0f + (float)(32 + l15) * (6.0f / 63.0f)) * 50.0f;
        const float c3 = (-3.0f + (float)(48 + l15) * (6.0f / 63.0f)) * 50.0f;
        ncb01 = (f2){-c0, -c1};
        ncb23 = (f2){-c2, -c3};
    }
    const f2 one2 = {1.0f, 1.0f};

    f32x4 acc[16];                         // acc[mt*4+nt]
#pragma unroll
    for (int i = 0; i < 16; ++i) acc[i] = (f32x4){0.f, 0.f, 0.f, 0.f};

    const int px0 = chunk * PX_PER_CHUNK + wv * PX_PER_WAVE;

    // prefetch super-tile 0
    float pr, pg, pb;
    {
        const int n = px0 + lane;
        pr = src[n]; pg = src[N_PIX + n]; pb = src[2 * N_PIX + n];
    }

#pragma unroll 1
    for (int st = 0; st < N_TILES; ++st) {
        // ---- Phase A: one pixel per lane; stage to LDS (same-wave, in-order) ----
        const float4 uvw = phaseA(pr, pg, pb, c);
        *(float4*)(wbuf + lane * 4 + (lane >> 3) * 4) = uvw;

        if (st + 1 < N_TILES) {            // prefetch next tile's raw pixels
            const int n2 = px0 + (st + 1) * 64 + lane;
            pr = src[n2]; pg = src[N_PIX + n2]; pb = src[2 * N_PIX + n2];
        }

#pragma unroll
        for (int h = 0; h < 2; ++h) {              // two K=32 halves
            const int base = h * 32 + quad * 8;    // first pixel this lane consumes
            const float4* __restrict__ pbase =
                (const float4*)(wbuf + base * 4 + (base >> 3) * 4);
            int aU[4][4], aV[4][4];                // fragment words [mt][jp]

#pragma unroll
            for (int jp = 0; jp < 4; ++jp) {       // j = 2jp (even), 2jp+1 (odd)
                const float4 pe = pbase[2 * jp];
                const float4 po = pbase[2 * jp + 1];

                f2 aue01, aue23, auo01, auo23;
                f2 bve01, bve23, bvo01, bvo23;
#pragma unroll
                for (int eo = 0; eo < 2; ++eo) {
                    const float ru = eo ? po.x : pe.x;
                    const float rv = eo ? po.y : pe.y;
                    const float rw = eo ? po.z : pe.z;
                    const f2 ru2 = {ru, ru}, rv2 = {rv, rv}, rw2 = {rw, rw};
                    const f2 tu01 = ru2 + ncb01, tu23 = ru2 + ncb23;
                    const f2 tv01 = rv2 + ncb01, tv23 = rv2 + ncb23;
                    const f2 qu01 = __builtin_elementwise_fma(tu01, tu01, one2);
                    const f2 qu23 = __builtin_elementwise_fma(tu23, tu23, one2);
                    const f2 qv01 = __builtin_elementwise_fma(tv01, tv01, one2);
                    const f2 qv23 = __builtin_elementwise_fma(tv23, tv23, one2);
                    // one rcp per denominator: trans pipe co-issues with VALU;
                    // V needs ZERO multiplies (rcp is the value), U just *w.
                    const f2 au01 = (f2){rcp_fast(qu01.x), rcp_fast(qu01.y)} * rw2;
                    const f2 au23 = (f2){rcp_fast(qu23.x), rcp_fast(qu23.y)} * rw2;
                    const f2 bv01 = {rcp_fast(qv01.x), rcp_fast(qv01.y)};
                    const f2 bv23 = {rcp_fast(qv23.x), rcp_fast(qv23.y)};
                    if (eo) { auo01 = au01; auo23 = au23; bvo01 = bv01; bvo23 = bv23; }
                    else    { aue01 = au01; aue23 = au23; bve01 = bv01; bve23 = bv23; }
                }
                aU[0][jp] = pk_bf16(aue01.x, auo01.x);   // mt0 <- center c0
                aU[1][jp] = pk_bf16(aue01.y, auo01.y);   // mt1 <- c1
                aU[2][jp] = pk_bf16(aue23.x, auo23.x);   // mt2 <- c2
                aU[3][jp] = pk_bf16(aue23.y, auo23.y);   // mt3 <- c3
                aV[0][jp] = pk_bf16(bve01.x, bvo01.x);
                aV[1][jp] = pk_bf16(bve01.y, bvo01.y);
                aV[2][jp] = pk_bf16(bve23.x, bvo23.x);
                aV[3][jp] = pk_bf16(bve23.y, bvo23.y);
            }

            short8 af[4], bf[4];
#pragma unroll
            for (int mt = 0; mt < 4; ++mt) {
                af[mt] = __builtin_bit_cast(short8,
                    make_int4(aU[mt][0], aU[mt][1], aU[mt][2], aU[mt][3]));
                bf[mt] = __builtin_bit_cast(short8,
                    make_int4(aV[mt][0], aV[mt][1], aV[mt][2], aV[mt][3]));
            }
#pragma unroll
            for (int mt = 0; mt < 4; ++mt)
#pragma unroll
                for (int nt = 0; nt < 4; ++nt)
                    acc[mt * 4 + nt] = __builtin_amdgcn_mfma_f32_16x16x32_bf16(
                        af[mt], bf[nt], acc[mt * 4 + nt], 0, 0, 0);
        }
    }

    // ---- Atomic-free epilogue: 4 chunks over mt; ALL traffic linear b128 ----
    float* __restrict__ outp = partial + (size_t)blk * 4096;
#pragma unroll 1
    for (int ch = 0; ch < 4; ++ch) {
        __syncthreads();                   // previous chunk (or main loop) done
#pragma unroll
        for (int nt = 0; nt < 4; ++nt)     // wave strip: [wv][nt*256 + lane*4 + i]
            *(f32x4*)(lds + wv * 1024 + nt * 256 + lane * 4) = acc[ch * 4 + nt];
        __syncthreads();
        const int e4 = tid * 4;            // 0..1023, linear -> conflict-free b128
        const f32x4 s0 = *(const f32x4*)(lds +        e4);
        const f32x4 s1 = *(const f32x4*)(lds + 1024 + e4);
        const f32x4 s2 = *(const f32x4*)(lds + 2048 + e4);
        const f32x4 s3 = *(const f32x4*)(lds + 3072 + e4);
        const f32x4 s = (s0 + s1) + (s2 + s3);
        // contiguous f32x4 store in wave-strip element order (no permutation;
        // bin mapping is job-independent so element e is consistent x vs y)
        *(f32x4*)(outp + ch * 1024 + e4) = s;
    }
}

// ---------------------------------------------------------------------------
// Kernel 2: Bhattacharyya-factored reduction + fused finalize.
//   sum (sqrt(y/TY)-sqrt(x/TX))^2 = 2(1 - rho), rho = sum sqrt(sx*sy)/sqrt(TX*TY)
// 96 blocks x 256 (24 x-jobs x 4 slices): each thread owns one element-QUAD;
// accumulates qx, qy over the 32 chunk-partials with contiguous f32x4 loads,
// then sx=Σqx, sy=Σqy, cr=Σ sqrt(qx*qy). Block-reduce 3 scalars, 3 device
// atomicAdds; tid0 RELEASE-ticket; the 96th block ACQUIRE-loads accum and
// writes out[0].
// ---------------------------------------------------------------------------
__global__ __launch_bounds__(256) void reduce_cross_kernel(
    const float* __restrict__ partial, float* __restrict__ accum,
    float* __restrict__ out)
{
    unsigned* __restrict__ ticket = (unsigned*)(accum + 24);
    const int jx = blockIdx.x >> 2;                        // 0..23 (img0 job)
    const int bb = jx / 3;                                 // batch 0..7
    const int e4 = (((blockIdx.x & 3) << 8) | threadIdx.x) * 4;  // 0..4092
    const float* px = partial + (size_t)jx * CHUNKS * 4096 + e4;
    const float* py = partial + (size_t)(24 + jx) * CHUNKS * 4096 + e4;

    f32x4 qx = {0.f, 0.f, 0.f, 0.f}, qy = {0.f, 0.f, 0.f, 0.f};
#pragma unroll 8
    for (int k = 0; k < CHUNKS; ++k) {
        qx += *(const f32x4*)(px + (size_t)k * 4096);
        qy += *(const f32x4*)(py + (size_t)k * 4096);
    }
    float sx = (qx.x + qx.y) + (qx.z + qx.w);
    float sy = (qy.x + qy.y) + (qy.z + qy.w);
    float cr = (sqrtf(qx.x * qy.x) + sqrtf(qx.y * qy.y)) +
               (sqrtf(qx.z * qy.z) + sqrtf(qx.w * qy.w));

#pragma unroll
    for (int o = 32; o > 0; o >>= 1) {
        sx += __shfl_down(sx, o, 64);
        sy += __shfl_down(sy, o, 64);
        cr += __shfl_down(cr, o, 64);
    }
    __shared__ float red[12];
    const int wv = threadIdx.x >> 6;
    if ((threadIdx.x & 63) == 0) {
        red[wv] = sx; red[4 + wv] = sy; red[8 + wv] = cr;
    }
    __syncthreads();
    if (threadIdx.x == 0) {
        atomicAdd(&accum[bb],      red[0] + red[1] + red[2] + red[3]);
        atomicAdd(&accum[8 + bb],  red[4] + red[5] + red[6] + red[7]);
        atomicAdd(&accum[16 + bb], red[8] + red[9] + red[10] + red[11]);
        const unsigned old = __hip_atomic_fetch_add(ticket, 1u,
                                 __ATOMIC_ACQ_REL, __HIP_MEMORY_SCOPE_AGENT);
        if (old == N_RBLOCKS - 1) {        // last arriver: all atomicAdds visible
            float s = 0.0f;
#pragma unroll
            for (int b = 0; b < 8; ++b) {
                const float tx = __hip_atomic_load(&accum[b],      __ATOMIC_ACQUIRE, __HIP_MEMORY_SCOPE_AGENT);
                const float ty = __hip_atomic_load(&accum[8 + b],  __ATOMIC_ACQUIRE, __HIP_MEMORY_SCOPE_AGENT);
                const float cc = __hip_atomic_load(&accum[16 + b], __ATOMIC_ACQUIRE, __HIP_MEMORY_SCOPE_AGENT);
                const float rho = cc * __builtin_amdgcn_rsqf(tx * ty);
                s += sqrtf(fmaxf(1.0f - rho, 0.0f));
            }
            out[0] = s * 0.125f;
        }
    }
}

extern "C" void kernel_launch(void* const* d_in, const int* in_sizes, int n_in,
                              void* d_out, int out_size, void* d_ws, size_t ws_size,
                              hipStream_t stream)
{
    const float* x = (const float*)d_in[0];
    const float* y = (const float*)d_in[1];
    float* ws = (float*)d_ws;
    float* partial = ws;                                  // 1536*4096 floats (25.2 MB)
    float* accum = ws + (size_t)N_BLOCKS * 4096;          // 24 floats + ticket
    float* outf = (float*)d_out;

    hipLaunchKernelGGL(hist_kernel, dim3(N_BLOCKS), dim3(256), 0, stream,
                       x, y, partial, accum);
    hipLaunchKernelGGL(reduce_cross_kernel, dim3(N_RBLOCKS), dim3(256), 0, stream,
                       partial, accum, outf);
}